// Round 2
// baseline (210.041 us; speedup 1.0000x reference)
//
#include <hip/hip_runtime.h>
#include <hip/hip_bf16.h>

// CTC batch cost — split-phase, LINEAR-domain f64, FORWARD+BACKWARD meet in
// the middle: 128 sequential iterations instead of 255.
//   P = sum_s alpha_127[s] * beta_127[s]
// Forward: lane i holds alpha[2i] (lo), alpha[2i+1] (hi).
// Backward: lane i holds beta[2i+1] (a), beta[2i+2] (b); beta[0] in lane 32's a.
// B=1024, T=256, C=128, L=32, S=65, blank=127.
//
// R1: phase-1 gather is fully coalesced (float2/lane = 512B global_load_dwordx2
//     per row) + 2 ds_bpermute to pull the 34 needed columns. lp contents
//     bit-identical to the verified 203.7us kernel.
// R2: phase-2 cross-lane shifts converted from ds_bpermute (~120cy DS latency
//     on the serial critical path, 1 wave/SIMD so nothing hides it) to DPP
//     wave_shr:1 / wave_shl:1 register moves (VALU latency). Lane-32's
//     beta[1] pull is patched via readfirstlane + cndmask. #pragma unroll 4
//     batches the 5 ds_read/iter under one lgkm wait.

#define CTC_B 1024
#define CTC_T 256
#define CTC_C 128
#define CTC_L 32
#define CTC_BLANK 127
#define CTC_EPS 1e-7f

#define RSTRIDE 34   // 32 labels + blank(32) + zero slot(33)

#define DPP_WAVE_SHL1 0x130   // lane i <- lane i+1, lane 63 <- 0 (bound_ctrl)
#define DPP_WAVE_SHR1 0x138   // lane i <- lane i-1, lane 0  <- 0 (bound_ctrl)

__device__ __forceinline__ double bperm_f64(int addr, double v) {
    union { double d; int i[2]; } u; u.d = v;
    int x = __builtin_amdgcn_ds_bpermute(addr, u.i[0]);
    int y = __builtin_amdgcn_ds_bpermute(addr, u.i[1]);
    union { int i[2]; double d; } r; r.i[0] = x; r.i[1] = y;
    return r.d;
}

// lane i <- lane i-1 (lane 0 <- 0): forward alpha[2i-1] shift
__device__ __forceinline__ double dpp_shr1_f64(double v) {
    union { double d; int i[2]; } u; u.d = v;
    int x = __builtin_amdgcn_update_dpp(0, u.i[0], DPP_WAVE_SHR1, 0xF, 0xF, true);
    int y = __builtin_amdgcn_update_dpp(0, u.i[1], DPP_WAVE_SHR1, 0xF, 0xF, true);
    union { int i[2]; double d; } r; r.i[0] = x; r.i[1] = y;
    return r.d;
}

// lane i <- lane i+1 (lane 63 <- 0): backward beta shift
__device__ __forceinline__ double dpp_shl1_f64(double v) {
    union { double d; int i[2]; } u; u.d = v;
    int x = __builtin_amdgcn_update_dpp(0, u.i[0], DPP_WAVE_SHL1, 0xF, 0xF, true);
    int y = __builtin_amdgcn_update_dpp(0, u.i[1], DPP_WAVE_SHL1, 0xF, 0xF, true);
    union { int i[2]; double d; } r; r.i[0] = x; r.i[1] = y;
    return r.d;
}

// broadcast lane 0's value to all lanes (readfirstlane: wave 0 all-active here)
__device__ __forceinline__ double bcast0_f64(double v) {
    union { double d; int i[2]; } u; u.d = v;
    int x = __builtin_amdgcn_readfirstlane(u.i[0]);
    int y = __builtin_amdgcn_readfirstlane(u.i[1]);
    union { int i[2]; double d; } r; r.i[0] = x; r.i[1] = y;
    return r.d;
}

__global__ __launch_bounds__(256) void ctc_loss_kernel(
    const int* __restrict__ y_true,   // [B, L] int32
    const float* __restrict__ y_pred, // [B, T, C] float32
    float* __restrict__ out)          // [B, 1] float32
{
    __shared__ float lp[CTC_T * RSTRIDE];  // 34.8 KB -> 4 blocks/CU

    const int b = blockIdx.x;
    const int tid = threadIdx.x;
    const int lane = tid & 63;
    const int wave = tid >> 6;

    const float* yp = y_pred + (size_t)b * CTC_T * CTC_C;

    // per-lane gather label: lanes 0..31 -> y_true, others -> blank
    int lbl = CTC_BLANK;
    if (lane < CTC_L) lbl = y_true[b * CTC_L + lane];

    // ---- phase 1: wave w fills t in [w*64, w*64+64); slot 33 = 0 ----
    // Coalesced: lane holds cols [2*lane, 2*lane+1] of row t; column lbl
    // lives in lane (lbl>>1), component (lbl&1). Pull via ds_bpermute.
    {
        const int t0 = wave * 64;
        const int src_addr = (lbl >> 1) << 2;   // byte addr of source lane
        const bool odd = (lbl & 1) != 0;
        #pragma unroll 8
        for (int k = 0; k < 64; ++k) {
            const int t = t0 + k;
            const float2 r =
                *reinterpret_cast<const float2*>(yp + (size_t)t * CTC_C + 2 * lane);
            union { float f; int i; } c0, c1;
            c0.f = r.x; c1.f = r.y;
            int g0 = __builtin_amdgcn_ds_bpermute(src_addr, c0.i);
            int g1 = __builtin_amdgcn_ds_bpermute(src_addr, c1.i);
            union { int i; float f; } s0, s1;
            s0.i = g0; s1.i = g1;
            float p = odd ? s1.f : s0.f;
            float v = (lane == 33) ? 0.0f : (p + CTC_EPS) * 128.0f;
            if (lane <= 33) lp[t * RSTRIDE + lane] = v;
        }
    }
    __syncthreads();

    if (wave != 0) return;

    // ---- per-lane constants ----
    // forward skip: state 2i+1 may come from 2i-1 iff y[i] != y[i-1]
    double skip = 0.0;
    if (lane >= 1 && lane < CTC_L) {
        if (y_true[b * CTC_L + lane - 1] != lbl) skip = 1.0;
    }
    // backward skip-in: state 2i+3 reachable from 2i+1 iff y[i+1] != y[i]
    double skipn = 0.0;
    if (lane <= 30) {
        if (y_true[b * CTC_L + lane + 1] != lbl) skipn = 1.0;
    } else if (lane == 32) {
        skipn = 1.0;   // reuse v-term as the 0 -> 1 transition
    }

    const int lidx = (lane < 32) ? lane : 32;          // own label slot
    const int pv_idx = (lane < 32) ? lane : 33;        // fwd label (0 if dead)
    const int tn = (lane <= 30) ? (lane + 1)
                 : (lane == 31) ? 33                    // state 65: killed
                 : (lane == 32) ? 0                     // beta[0] uses p[1]
                 : 32;                                  // dead: harmless
    const int pbi = (lane == 32) ? 33 : 32;            // bwd blank (0 @ 32)

    const bool is32 = (lane == 32);                    // beta[1] patch mask

    // ---- init ----
    double lo = 0.0, hi = 0.0;          // alpha
    if (lane == 0) {
        lo = (double)lp[32];            // alpha[0] = blank @ t=0
        hi = (double)lp[0];             // alpha[1] = label0 @ t=0
    }
    double a = 0.0, bb = 0.0;           // beta (a = odd 2i+1, bb = even 2i+2)
    if (lane == 31) { a = 1.0; bb = 1.0; }   // beta_255[63] = beta_255[64] = 1

    // ---- 127 interleaved iterations: fwd t=1..127, bwd t=255..129 ----
    // DPP shifts: fwd needs lane-1's hi (lane 0 <- 0 == old behavior, since
    // lane 63's hi is provably always 0). bwd needs lane+1's a, except
    // lane 32 needs lane 0's a (beta[1]) — patched with bcast + cndmask.
    // Lane 63 <- 0 via bound_ctrl is harmless (lane 63 state is dead-zero).
    #pragma unroll 4
    for (int k = 0; k < 127; ++k) {
        const int tf = 1 + k;
        const int tb = 255 - k;
        float pvf  = lp[tf * RSTRIDE + pv_idx];
        float pbf  = lp[tf * RSTRIDE + 32];
        float paf  = lp[tb * RSTRIDE + lidx];
        float pa1f = lp[tb * RSTRIDE + tn];
        float pbbf = lp[tb * RSTRIDE + pbi];

        // register-only cross-lane shifts (no DS on the critical path)
        double ph  = dpp_shr1_f64(hi);             // alpha[2i-1]; lane0 <- 0
        double a1s = dpp_shl1_f64(a);              // a from lane+1
        double a1  = is32 ? bcast0_f64(a) : a1s;   // lane32 <- beta[1]

        // forward
        double nl = (lo + ph) * (double)pbf;
        double nh = (hi + lo + skip * ph) * (double)pvf;
        // backward
        double v  = (double)pa1f * a1;
        double u  = (double)pbbf * bb;
        double nb = u + v;
        double na = fma((double)paf, a, fma(skipn, v, u));

        lo = nl; hi = nh; a = na; bb = nb;
    }

    // ---- final backward-only step: tb = 128 -> beta_127 ----
    {
        const int tb = 128;
        float paf  = lp[tb * RSTRIDE + lidx];
        float pa1f = lp[tb * RSTRIDE + tn];
        float pbbf = lp[tb * RSTRIDE + pbi];
        double a1s = dpp_shl1_f64(a);
        double a1  = is32 ? bcast0_f64(a) : a1s;
        double v  = (double)pa1f * a1;
        double u  = (double)pbbf * bb;
        double nb = u + v;
        double na = fma((double)paf, a, fma(skipn, v, u));
        a = na; bb = nb;
    }

    // ---- combine: P = sum_s alpha_127[s] * beta_127[s] ----
    // beta[2i]: i=0 -> a_32 (beta[0]); i>=1 -> bb_{i-1}
    double beA = bperm_f64(32 << 2, a);                      // all: a_32
    double beB = bperm_f64(((lane + 63) & 63) << 2, bb);     // bb_{i-1}
    double be = (lane == 0) ? beA : beB;
    double partial = (lane <= 32) ? (lo * be + hi * a) : 0.0;
    #pragma unroll
    for (int off = 32; off >= 1; off >>= 1)
        partial += __shfl_down(partial, off);
    if (lane == 0) {
        out[b] = (float)(1242.1197475634219 - log(partial)); // 256*ln(128)
    }
}

extern "C" void kernel_launch(void* const* d_in, const int* in_sizes, int n_in,
                              void* d_out, int out_size, void* d_ws, size_t ws_size,
                              hipStream_t stream) {
    const int*   y_true = (const int*)d_in[0];
    const float* y_pred = (const float*)d_in[1];
    float*       out    = (float*)d_out;

    ctc_loss_kernel<<<CTC_B, 256, 0, stream>>>(y_true, y_pred, out);
}